// Round 7
// baseline (590.479 us; speedup 1.0000x reference)
//
#include <hip/hip_runtime.h>
#include <cstdint>
#include <cstddef>

#define NV 5
#define NC 128
#define NT 128
#define NB 128
typedef unsigned long long ull;

__device__ __forceinline__ float fa(float a, float b){ return __fadd_rn(a,b); }
__device__ __forceinline__ float fm(float a, float b){ return __fmul_rn(a,b); }
__device__ __forceinline__ float fs(float a, float b){ return __fsub_rn(a,b); }

// numpy pairwise_sum base case, n=80, contiguous fp32
__device__ __forceinline__ float base80(const float* a)
{
    float r0=a[0],r1=a[1],r2=a[2],r3=a[3],r4=a[4],r5=a[5],r6=a[6],r7=a[7];
    #pragma unroll
    for (int i = 8; i < 80; i += 8) {
        r0=fa(r0,a[i+0]); r1=fa(r1,a[i+1]); r2=fa(r2,a[i+2]); r3=fa(r3,a[i+3]);
        r4=fa(r4,a[i+4]); r5=fa(r5,a[i+5]); r6=fa(r6,a[i+6]); r7=fa(r7,a[i+7]);
    }
    return fa(fa(fa(r0,r1),fa(r2,r3)), fa(fa(r4,r5),fa(r6,r7)));
}

// =========================================================================
// Kernel A: np-mimic fp32 fusion matmul + GroupNorm1 (pairwise stats).
// 4 samples/block, 128 threads (thread = output channel o). grid = 4096.
// y1 (fp32, 41.9MB) -> d_ws.
// =========================================================================
__global__ __launch_bounds__(128) void kA(const float* __restrict__ x,
                                          const float* __restrict__ W,
                                          const float* __restrict__ g1w,
                                          const float* __restrict__ g1b,
                                          float* __restrict__ y1)
{
    const int n0 = blockIdx.x * 4;
    const int o  = threadIdx.x;            // 0..127
    const float* wa = W + (size_t)o * 256;
    const float* xp = x + (size_t)n0 * 1280;

    float acc[4][NV];
    #pragma unroll
    for (int g = 0; g < 4; ++g)
        #pragma unroll
        for (int v = 0; v < NV; ++v) acc[g][v] = 0.f;

    // c = 0..127 : acc-part (fused channels 0..127), sequential, unfused
    for (int c = 0; c < NC; ++c) {
        const float A = wa[c];
        #pragma unroll
        for (int g = 0; g < 4; ++g) {
            const float* xr = xp + (size_t)g * 1280 + c * 10;
            #pragma unroll
            for (int v = 0; v < NV; ++v)
                acc[g][v] = fa(acc[g][v], fm(A, xr[v]));
        }
    }
    // c = 128..255 : gyr-part (fused channels 128..255), sequential
    for (int c = 0; c < NC; ++c) {
        const float G = wa[128 + c];
        #pragma unroll
        for (int g = 0; g < 4; ++g) {
            const float* xr = xp + (size_t)g * 1280 + c * 10;
            #pragma unroll
            for (int v = 0; v < NV; ++v)
                acc[g][v] = fa(acc[g][v], fm(G, xr[5 + v]));
        }
    }

    __shared__ float ys[4][640];
    __shared__ float ds[4][640];
    __shared__ float statA[4][4];
    __shared__ float muS[4], rstdS[4];

    #pragma unroll
    for (int g = 0; g < 4; ++g)
        #pragma unroll
        for (int v = 0; v < NV; ++v) ys[g][o * 5 + v] = acc[g][v];
    __syncthreads();

    // mean: numpy pairwise over 640 (o-major order)
    if (threadIdx.x < 16) {
        const int g = threadIdx.x >> 2, p = threadIdx.x & 3;
        const float b0 = base80(&ys[g][(2 * p) * 80]);
        const float b1 = base80(&ys[g][(2 * p + 1) * 80]);
        statA[g][p] = fa(b0, b1);
    }
    __syncthreads();
    if (threadIdx.x < 4) {
        const int g = threadIdx.x;
        const float tot = fa(fa(statA[g][0], statA[g][1]), fa(statA[g][2], statA[g][3]));
        muS[g] = __fdiv_rn(tot, 640.f);
    }
    __syncthreads();

    // var: x = a - mu (fp32), x*x (fp32), pairwise / 640
    #pragma unroll
    for (int g = 0; g < 4; ++g) {
        const float mu = muS[g];
        #pragma unroll
        for (int v = 0; v < NV; ++v) {
            const float d = fs(acc[g][v], mu);
            ds[g][o * 5 + v] = fm(d, d);
        }
    }
    __syncthreads();
    if (threadIdx.x < 16) {
        const int g = threadIdx.x >> 2, p = threadIdx.x & 3;
        const float b0 = base80(&ds[g][(2 * p) * 80]);
        const float b1 = base80(&ds[g][(2 * p + 1) * 80]);
        statA[g][p] = fa(b0, b1);
    }
    __syncthreads();
    if (threadIdx.x < 4) {
        const int g = threadIdx.x;
        const float tot = fa(fa(statA[g][0], statA[g][1]), fa(statA[g][2], statA[g][3]));
        const float var = __fdiv_rn(tot, 640.f);
        rstdS[g] = __fdiv_rn(1.f, __fsqrt_rn(fa(var, 1e-5f)));
    }
    __syncthreads();

    const float wf = g1w[o], bf = g1b[o];
    #pragma unroll
    for (int g = 0; g < 4; ++g) {
        const float mu = muS[g], rstd = rstdS[g];
        const int n = n0 + g;
        #pragma unroll
        for (int v = 0; v < NV; ++v) {
            const float xn = fm(fs(acc[g][v], mu), rstd);
            y1[(size_t)n * 640 + o * 5 + v] = fa(fm(xn, wf), bf);
        }
    }
}

// =========================================================================
// Kernel B: LIF1 (fp32, bitmask) -> masked conv (np order) -> GN2 (pairwise)
// -> LIF2 -> duplicated binary output. grid = B*2 = 256, block = 320.
// =========================================================================
__device__ __forceinline__ float bitf(ull lo, ull hi, int t)
{
    if (t < 0 || t > 127) return 0.f;
    return (float)(((t < 64) ? (lo >> t) : (hi >> (t - 64))) & 1ull);
}

__device__ __forceinline__ float conv_np(const float* __restrict__ mw,
                                         const ull* __restrict__ slo,
                                         const ull* __restrict__ shi,
                                         int node, int t)
{
    float res = 0.f;
    #pragma unroll
    for (int i = 0; i < 5; ++i)
        #pragma unroll
        for (int k = 0; k < 3; ++k)
            res = fa(res, fm(mw[(node * 5 + i) * 3 + k], bitf(slo[i], shi[i], t - 1 + k)));
    return res;
}

__global__ __launch_bounds__(320) void kB(const float* __restrict__ y1,
                                          const float* __restrict__ Wm,
                                          const float* __restrict__ g2w,
                                          const float* __restrict__ g2b,
                                          const float* __restrict__ adj,
                                          float* __restrict__ out)
{
    const int b   = blockIdx.x >> 1;
    const int ch  = blockIdx.x & 1;
    const int tid = threadIdx.x;           // 0..319
    const int cl  = tid / NV;              // 0..63
    const int o   = tid - cl * NV;         // 0..4 (node)
    const int c   = ch * 64 + cl;

    __shared__ float mw_s[75];
    __shared__ ull mlo[320], mhi[320];
    __shared__ float statS[64][4];
    __shared__ float muS[64], rstdS[64];

    if (tid < 75) {
        const int oo = tid / 15, rem = tid % 15, ii = rem / 3;
        const float sym = fm(0.5f, fa(adj[oo * 5 + ii], adj[ii * 5 + oo]));
        const float e = (float)exp(-(double)sym);          // ~correctly-rounded fp32 exp
        const float sig = __fdiv_rn(1.f, fa(1.f, e));
        mw_s[tid] = fm(Wm[tid], sig);
    }

    // ---- LIF1 (fp32), spikes to bitmask
    ull lo = 0ull, hi = 0ull;
    {
        float vm = 0.f;
        const float* p = y1 + (size_t)b * 640 + (size_t)c * 5 + o;
        for (int t = 0; t < NT; ++t) {
            const float xv = p[(size_t)t * (NB * 640)];
            vm = fa(vm, fm(fs(xv, vm), 0.5f));
            if (vm >= 0.8f) {
                if (t < 64) lo |= 1ull << t; else hi |= 1ull << (t - 64);
                vm = 0.f;
            }
        }
    }
    mlo[tid] = lo; mhi[tid] = hi;
    __syncthreads();

    ull slo[NV], shi[NV];
    #pragma unroll
    for (int i = 0; i < NV; ++i) { slo[i] = mlo[cl * 5 + i]; shi[i] = mhi[cl * 5 + i]; }

    // ---- GN2 mean: numpy pairwise over 640 in (node, t) memory order
    if (o < 4) {
        float bsum[2];
        #pragma unroll
        for (int h = 0; h < 2; ++h) {
            const int base = (2 * o + h) * 80;
            float r[8];
            #pragma unroll
            for (int j = 0; j < 8; ++j) {
                const int idx = base + j;
                r[j] = conv_np(mw_s, slo, shi, idx >> 7, idx & 127);
            }
            #pragma unroll
            for (int i = 8; i < 80; i += 8)
                #pragma unroll
                for (int j = 0; j < 8; ++j) {
                    const int idx = base + i + j;
                    r[j] = fa(r[j], conv_np(mw_s, slo, shi, idx >> 7, idx & 127));
                }
            bsum[h] = fa(fa(fa(r[0],r[1]),fa(r[2],r[3])), fa(fa(r[4],r[5]),fa(r[6],r[7])));
        }
        statS[cl][o] = fa(bsum[0], bsum[1]);
    }
    __syncthreads();
    if (o == 0) {
        const float tot = fa(fa(statS[cl][0], statS[cl][1]), fa(statS[cl][2], statS[cl][3]));
        muS[cl] = __fdiv_rn(tot, 640.f);
    }
    __syncthreads();

    // ---- GN2 var: pairwise over (conv - mu)^2
    if (o < 4) {
        const float mu = muS[cl];
        float bsum[2];
        #pragma unroll
        for (int h = 0; h < 2; ++h) {
            const int base = (2 * o + h) * 80;
            float r[8];
            #pragma unroll
            for (int j = 0; j < 8; ++j) {
                const int idx = base + j;
                const float d = fs(conv_np(mw_s, slo, shi, idx >> 7, idx & 127), mu);
                r[j] = fm(d, d);
            }
            #pragma unroll
            for (int i = 8; i < 80; i += 8)
                #pragma unroll
                for (int j = 0; j < 8; ++j) {
                    const int idx = base + i + j;
                    const float d = fs(conv_np(mw_s, slo, shi, idx >> 7, idx & 127), mu);
                    r[j] = fa(r[j], fm(d, d));
                }
            bsum[h] = fa(fa(fa(r[0],r[1]),fa(r[2],r[3])), fa(fa(r[4],r[5]),fa(r[6],r[7])));
        }
        statS[cl][o] = fa(bsum[0], bsum[1]);
    }
    __syncthreads();
    if (o == 0) {
        const float tot = fa(fa(statS[cl][0], statS[cl][1]), fa(statS[cl][2], statS[cl][3]));
        const float var = __fdiv_rn(tot, 640.f);
        rstdS[cl] = __fdiv_rn(1.f, __fsqrt_rn(fa(var, 1e-5f)));
    }
    __syncthreads();

    // ---- GN2 normalize -> LIF2 -> duplicated output
    const float mu = muS[cl], rstd = rstdS[cl];
    const float gw = g2w[o], gb = g2b[o];
    float vm = 0.f;
    const size_t cbase = (size_t)c * 10 + o;
    for (int t = 0; t < NT; ++t) {
        const float z  = conv_np(mw_s, slo, shi, o, t);
        const float xn = fm(fs(z, mu), rstd);
        const float yn = fa(fm(xn, gw), gb);
        vm = fa(vm, fm(fs(yn, vm), 0.5f));
        const bool sp = (vm >= 0.8f);
        if (sp) vm = 0.f;
        const float so = sp ? 1.f : 0.f;
        const size_t e = (size_t)(t * NB + b) * 1280 + cbase;
        out[e]     = so;
        out[e + 5] = so;
    }
}

// =========================================================================
extern "C" void kernel_launch(void* const* d_in, const int* in_sizes, int n_in,
                              void* d_out, int out_size, void* d_ws, size_t ws_size,
                              hipStream_t stream)
{
    const float* x   = (const float*)d_in[0];
    const float* W   = (const float*)d_in[1];
    const float* g1w = (const float*)d_in[2];
    const float* g1b = (const float*)d_in[3];
    const float* Wm  = (const float*)d_in[4];
    const float* g2w = (const float*)d_in[5];
    const float* g2b = (const float*)d_in[6];
    const float* adj = (const float*)d_in[7];
    float* out = (float*)d_out;
    float* y1  = (float*)d_ws;   // 10.49M fp32 = 41.9MB (ws measured >= 256MB)

    hipLaunchKernelGGL(kA, dim3(NT * NB / 4), dim3(128), 0, stream,
                       x, W, g1w, g1b, y1);
    hipLaunchKernelGGL(kB, dim3(NB * 2), dim3(320), 0, stream,
                       y1, Wm, g2w, g2b, adj, out);
}

// Round 8
// 270.163 us; speedup vs baseline: 2.1856x; 2.1856x over previous
//
#include <hip/hip_runtime.h>
#include <cstdint>
#include <cstddef>

#define NV 5
#define NC 128
#define NT 128
#define NB 128
typedef unsigned long long ull;

__device__ __forceinline__ float fa(float a, float b){ return __fadd_rn(a,b); }
__device__ __forceinline__ float fm(float a, float b){ return __fmul_rn(a,b); }
__device__ __forceinline__ float fs(float a, float b){ return __fsub_rn(a,b); }

// numpy pairwise_sum base case, n=80, contiguous fp32
__device__ __forceinline__ float base80(const float* a)
{
    float r0=a[0],r1=a[1],r2=a[2],r3=a[3],r4=a[4],r5=a[5],r6=a[6],r7=a[7];
    #pragma unroll
    for (int i = 8; i < 80; i += 8) {
        r0=fa(r0,a[i+0]); r1=fa(r1,a[i+1]); r2=fa(r2,a[i+2]); r3=fa(r3,a[i+3]);
        r4=fa(r4,a[i+4]); r5=fa(r5,a[i+5]); r6=fa(r6,a[i+6]); r7=fa(r7,a[i+7]);
    }
    return fa(fa(fa(r0,r1),fa(r2,r3)), fa(fa(r4,r5),fa(r6,r7)));
}

// base80 over (a[i]-mu)^2, identical op order to the var phase
__device__ __forceinline__ float base80v(const float* a, float mu)
{
    float r[8];
    #pragma unroll
    for (int j = 0; j < 8; ++j) { const float d = fs(a[j], mu); r[j] = fm(d, d); }
    #pragma unroll
    for (int i = 8; i < 80; i += 8)
        #pragma unroll
        for (int j = 0; j < 8; ++j) {
            const float d = fs(a[i + j], mu);
            r[j] = fa(r[j], fm(d, d));
        }
    return fa(fa(fa(r[0],r[1]),fa(r[2],r[3])), fa(fa(r[4],r[5]),fa(r[6],r[7])));
}

// =========================================================================
// Kernel A: UNCHANGED from the passing round (np-mimic matmul + GN1).
// =========================================================================
__global__ __launch_bounds__(128) void kA(const float* __restrict__ x,
                                          const float* __restrict__ W,
                                          const float* __restrict__ g1w,
                                          const float* __restrict__ g1b,
                                          float* __restrict__ y1)
{
    const int n0 = blockIdx.x * 4;
    const int o  = threadIdx.x;            // 0..127
    const float* wa = W + (size_t)o * 256;
    const float* xp = x + (size_t)n0 * 1280;

    float acc[4][NV];
    #pragma unroll
    for (int g = 0; g < 4; ++g)
        #pragma unroll
        for (int v = 0; v < NV; ++v) acc[g][v] = 0.f;

    for (int c = 0; c < NC; ++c) {
        const float A = wa[c];
        #pragma unroll
        for (int g = 0; g < 4; ++g) {
            const float* xr = xp + (size_t)g * 1280 + c * 10;
            #pragma unroll
            for (int v = 0; v < NV; ++v)
                acc[g][v] = fa(acc[g][v], fm(A, xr[v]));
        }
    }
    for (int c = 0; c < NC; ++c) {
        const float G = wa[128 + c];
        #pragma unroll
        for (int g = 0; g < 4; ++g) {
            const float* xr = xp + (size_t)g * 1280 + c * 10;
            #pragma unroll
            for (int v = 0; v < NV; ++v)
                acc[g][v] = fa(acc[g][v], fm(G, xr[5 + v]));
        }
    }

    __shared__ float ys[4][640];
    __shared__ float ds[4][640];
    __shared__ float statA[4][4];
    __shared__ float muS[4], rstdS[4];

    #pragma unroll
    for (int g = 0; g < 4; ++g)
        #pragma unroll
        for (int v = 0; v < NV; ++v) ys[g][o * 5 + v] = acc[g][v];
    __syncthreads();

    if (threadIdx.x < 16) {
        const int g = threadIdx.x >> 2, p = threadIdx.x & 3;
        const float b0 = base80(&ys[g][(2 * p) * 80]);
        const float b1 = base80(&ys[g][(2 * p + 1) * 80]);
        statA[g][p] = fa(b0, b1);
    }
    __syncthreads();
    if (threadIdx.x < 4) {
        const int g = threadIdx.x;
        const float tot = fa(fa(statA[g][0], statA[g][1]), fa(statA[g][2], statA[g][3]));
        muS[g] = __fdiv_rn(tot, 640.f);
    }
    __syncthreads();

    #pragma unroll
    for (int g = 0; g < 4; ++g) {
        const float mu = muS[g];
        #pragma unroll
        for (int v = 0; v < NV; ++v) {
            const float d = fs(acc[g][v], mu);
            ds[g][o * 5 + v] = fm(d, d);
        }
    }
    __syncthreads();
    if (threadIdx.x < 16) {
        const int g = threadIdx.x >> 2, p = threadIdx.x & 3;
        const float b0 = base80(&ds[g][(2 * p) * 80]);
        const float b1 = base80(&ds[g][(2 * p + 1) * 80]);
        statA[g][p] = fa(b0, b1);
    }
    __syncthreads();
    if (threadIdx.x < 4) {
        const int g = threadIdx.x;
        const float tot = fa(fa(statA[g][0], statA[g][1]), fa(statA[g][2], statA[g][3]));
        const float var = __fdiv_rn(tot, 640.f);
        rstdS[g] = __fdiv_rn(1.f, __fsqrt_rn(fa(var, 1e-5f)));
    }
    __syncthreads();

    const float wf = g1w[o], bf = g1b[o];
    #pragma unroll
    for (int g = 0; g < 4; ++g) {
        const float mu = muS[g], rstd = rstdS[g];
        const int n = n0 + g;
        #pragma unroll
        for (int v = 0; v < NV; ++v) {
            const float xn = fm(fs(acc[g][v], mu), rstd);
            y1[(size_t)n * 640 + o * 5 + v] = fa(fm(xn, wf), bf);
        }
    }
}

// =========================================================================
// Kernel B1: LIF1 (fp32, identical chain) -> ulonglong2 spike masks.
// grid = B*2 = 256 blocks, block = 320 threads. masks[(b*128+c)*5+v].
// =========================================================================
__global__ __launch_bounds__(320) void kB1(const float* __restrict__ y1,
                                           ulonglong2* __restrict__ masks)
{
    const int b   = blockIdx.x >> 1;
    const int c0  = (blockIdx.x & 1) * 64;
    const int tid = threadIdx.x;           // 0..319

    ull lo = 0ull, hi = 0ull;
    float vm = 0.f;
    const float* p = y1 + (size_t)b * 640 + (size_t)c0 * 5 + tid;
    for (int t0 = 0; t0 < NT; t0 += 16) {
        float xv[16];
        #pragma unroll
        for (int j = 0; j < 16; ++j)
            xv[j] = p[(size_t)(t0 + j) * (NB * 640)];
        #pragma unroll
        for (int j = 0; j < 16; ++j) {
            vm = fa(vm, fm(fs(xv[j], vm), 0.5f));
            if (vm >= 0.8f) {
                const int t = t0 + j;
                if (t < 64) lo |= 1ull << t; else hi |= 1ull << (t - 64);
                vm = 0.f;
            }
        }
    }
    masks[(size_t)b * 640 + (size_t)c0 * 5 + tid] = make_ulonglong2(lo, hi);
}

// =========================================================================
// Kernel B2: conv once (LDS) -> pairwise GN2 -> LIF2 -> coalesced stores.
// grid = 4096 blocks (b, c-quad), block = 512 = 4 pairs x 128 (thread = t).
// =========================================================================
__device__ __forceinline__ float bitf(ull lo, ull hi, int t)
{
    if (t < 0 || t > 127) return 0.f;
    return (float)(((t < 64) ? (lo >> t) : (hi >> (t - 64))) & 1ull);
}

__global__ __launch_bounds__(512) void kB2(const ulonglong2* __restrict__ masks,
                                           const float* __restrict__ Wm,
                                           const float* __restrict__ g2w,
                                           const float* __restrict__ g2b,
                                           const float* __restrict__ adj,
                                           float* __restrict__ out)
{
    const int blk = blockIdx.x;            // 0..4095
    const int b   = blk >> 5;              // 0..127
    const int c0  = (blk & 31) * 4;        // 0,4,..,124
    const int tid = threadIdx.x;           // 0..511
    const int p   = tid >> 7;              // pair 0..3
    const int lt  = tid & 127;             // t index / worker id

    __shared__ float mw_s[75];
    __shared__ ull   m_lo[4][5], m_hi[4][5];
    __shared__ float conv_s[4][5][128];
    __shared__ float spk_s[128][40];
    __shared__ float stat_s[4][8];
    __shared__ float mu_s[4], rstd_s[4];

    if (tid < 75) {
        const int oo = tid / 15, rem = tid % 15, ii = rem / 3;
        const float sym = fm(0.5f, fa(adj[oo * 5 + ii], adj[ii * 5 + oo]));
        const float e = (float)exp(-(double)sym);
        const float sig = __fdiv_rn(1.f, fa(1.f, e));
        mw_s[tid] = fm(Wm[tid], sig);
    }
    if (tid < 20) {
        const int pp = tid / 5, vv = tid % 5;
        const ulonglong2 m = masks[((size_t)b * 128 + c0 + pp) * 5 + vv];
        m_lo[pp][vv] = m.x; m_hi[pp][vv] = m.y;
    }
    __syncthreads();

    // ---- conv once: thread (p, t=lt); 15 shared bit extracts, 5 nodes
    {
        float bv[5][3];
        #pragma unroll
        for (int i = 0; i < 5; ++i) {
            const ull lo = m_lo[p][i], hi = m_hi[p][i];
            #pragma unroll
            for (int k = 0; k < 3; ++k)
                bv[i][k] = bitf(lo, hi, lt - 1 + k);
        }
        #pragma unroll
        for (int o = 0; o < 5; ++o) {
            float res = 0.f;
            #pragma unroll
            for (int i = 0; i < 5; ++i)
                #pragma unroll
                for (int k = 0; k < 3; ++k)
                    res = fa(res, fm(mw_s[(o * 5 + i) * 3 + k], bv[i][k]));
            conv_s[p][o][lt] = res;
        }
    }
    __syncthreads();

    // ---- GN2 mean: numpy pairwise over flat [5][128] (8 x base80)
    if (lt < 8)
        stat_s[p][lt] = base80(&conv_s[p][0][0] + lt * 80);
    __syncthreads();
    if (lt == 0) {
        const float* s = stat_s[p];
        const float tot = fa(fa(fa(s[0],s[1]),fa(s[2],s[3])),
                             fa(fa(s[4],s[5]),fa(s[6],s[7])));
        mu_s[p] = __fdiv_rn(tot, 640.f);
    }
    __syncthreads();

    // ---- GN2 var
    if (lt < 8)
        stat_s[p][lt] = base80v(&conv_s[p][0][0] + lt * 80, mu_s[p]);
    __syncthreads();
    if (lt == 0) {
        const float* s = stat_s[p];
        const float tot = fa(fa(fa(s[0],s[1]),fa(s[2],s[3])),
                             fa(fa(s[4],s[5]),fa(s[6],s[7])));
        const float var = __fdiv_rn(tot, 640.f);
        rstd_s[p] = __fdiv_rn(1.f, __fsqrt_rn(fa(var, 1e-5f)));
    }
    __syncthreads();

    // ---- LIF2: 5 threads per pair (o = lt), spikes -> LDS
    if (lt < 5) {
        const int o = lt;
        const float mu = mu_s[p], rstd = rstd_s[p];
        const float gw = g2w[o], gb = g2b[o];
        float vm = 0.f;
        for (int t = 0; t < NT; ++t) {
            const float z  = conv_s[p][o][t];
            const float xn = fm(fs(z, mu), rstd);
            const float yn = fa(fm(xn, gw), gb);
            vm = fa(vm, fm(fs(yn, vm), 0.5f));
            const bool sp = (vm >= 0.8f);
            if (sp) vm = 0.f;
            const float so = sp ? 1.f : 0.f;
            spk_s[t][p * 10 + o]     = so;
            spk_s[t][p * 10 + 5 + o] = so;
        }
    }
    __syncthreads();

    // ---- coalesced store: 1280 float4s cover out[(t,b), c0*10 .. c0*10+40)
    for (int q = tid; q < 1280; q += 512) {
        const int t = q / 10, s = q - t * 10;
        float4* dst = (float4*)(out + ((size_t)(t * NB + b) * 1280 + c0 * 10));
        dst[s] = reinterpret_cast<const float4*>(&spk_s[t][0])[s];
    }
}

// =========================================================================
extern "C" void kernel_launch(void* const* d_in, const int* in_sizes, int n_in,
                              void* d_out, int out_size, void* d_ws, size_t ws_size,
                              hipStream_t stream)
{
    const float* x   = (const float*)d_in[0];
    const float* W   = (const float*)d_in[1];
    const float* g1w = (const float*)d_in[2];
    const float* g1b = (const float*)d_in[3];
    const float* Wm  = (const float*)d_in[4];
    const float* g2w = (const float*)d_in[5];
    const float* g2b = (const float*)d_in[6];
    const float* adj = (const float*)d_in[7];
    float* out = (float*)d_out;

    float* y1 = (float*)d_ws;                                    // 41.9 MB
    ulonglong2* masks = (ulonglong2*)((char*)d_ws + (64u << 20)); // 1.3 MB

    hipLaunchKernelGGL(kA, dim3(NT * NB / 4), dim3(128), 0, stream,
                       x, W, g1w, g1b, y1);
    hipLaunchKernelGGL(kB1, dim3(NB * 2), dim3(320), 0, stream,
                       y1, masks);
    hipLaunchKernelGGL(kB2, dim3(4096), dim3(512), 0, stream,
                       masks, Wm, g2w, g2b, adj, out);
}

// Round 9
// 201.662 us; speedup vs baseline: 2.9281x; 1.3397x over previous
//
#include <hip/hip_runtime.h>
#include <cstdint>
#include <cstddef>

#define NV 5
#define NC 128
#define NT 128
#define NB 128
typedef unsigned long long ull;

__device__ __forceinline__ float fa(float a, float b){ return __fadd_rn(a,b); }
__device__ __forceinline__ float fm(float a, float b){ return __fmul_rn(a,b); }
__device__ __forceinline__ float fs(float a, float b){ return __fsub_rn(a,b); }

// numpy pairwise_sum base case, n=80, contiguous fp32
__device__ __forceinline__ float base80(const float* a)
{
    float r0=a[0],r1=a[1],r2=a[2],r3=a[3],r4=a[4],r5=a[5],r6=a[6],r7=a[7];
    #pragma unroll
    for (int i = 8; i < 80; i += 8) {
        r0=fa(r0,a[i+0]); r1=fa(r1,a[i+1]); r2=fa(r2,a[i+2]); r3=fa(r3,a[i+3]);
        r4=fa(r4,a[i+4]); r5=fa(r5,a[i+5]); r6=fa(r6,a[i+6]); r7=fa(r7,a[i+7]);
    }
    return fa(fa(fa(r0,r1),fa(r2,r3)), fa(fa(r4,r5),fa(r6,r7)));
}

// base80 over (a[i]-mu)^2, identical op order to the var phase
__device__ __forceinline__ float base80v(const float* a, float mu)
{
    float r[8];
    #pragma unroll
    for (int j = 0; j < 8; ++j) { const float d = fs(a[j], mu); r[j] = fm(d, d); }
    #pragma unroll
    for (int i = 8; i < 80; i += 8)
        #pragma unroll
        for (int j = 0; j < 8; ++j) {
            const float d = fs(a[i + j], mu);
            r[j] = fa(r[j], fm(d, d));
        }
    return fa(fa(fa(r[0],r[1]),fa(r[2],r[3])), fa(fa(r[4],r[5]),fa(r[6],r[7])));
}

// =========================================================================
// Kernel T: W[o][c] -> Wt[c][o]  (exact copy; enables coalesced kA reads)
// =========================================================================
__global__ __launch_bounds__(256) void kT(const float* __restrict__ W,
                                          float* __restrict__ Wt)
{
    const int i = blockIdx.x * 256 + threadIdx.x;   // 0..32767 = c*128+o
    const int c = i >> 7, o = i & 127;
    Wt[i] = W[o * 256 + c];
}

// =========================================================================
// Kernel A: np-mimic fp32 fusion matmul + GN1.
// 4 samples/block, 128 threads (thread = output channel o). grid = 4096.
// x-tile staged in LDS (broadcast reads); weights via transposed Wt
// (coalesced). Identical fp32 op sequence to the passing kernel.
// =========================================================================
__global__ __launch_bounds__(128) void kA(const float* __restrict__ x,
                                          const float* __restrict__ Wt,
                                          const float* __restrict__ g1w,
                                          const float* __restrict__ g1b,
                                          float* __restrict__ y1)
{
    const int n0 = blockIdx.x * 4;
    const int o  = threadIdx.x;            // 0..127

    __shared__ float xs_raw[4 * 256 * 8];  // 32 KB; [g][fc][8] then reused
    __shared__ float statA[4][4];
    __shared__ float muS[4], rstdS[4];
    float (*xs)[256][8] = (float (*)[256][8])xs_raw;

    // ---- stage x-tile: 5120 contiguous floats as 1280 coalesced float4
    {
        const float4* xg = (const float4*)(x + (size_t)n0 * 1280);
        #pragma unroll
        for (int it = 0; it < 10; ++it) {
            const int q = it * 128 + o;        // float4 index 0..1279
            const float4 val = xg[q];
            const int f = q * 4;               // flat float index (g*1280 + r)
            const int g = f >> 10 >> 0 ? f / 1280 : 0;  // f/1280
            const int gg = f / 1280;
            int r = f - gg * 1280;
            float tmp[4] = {val.x, val.y, val.z, val.w};
            #pragma unroll
            for (int e = 0; e < 4; ++e) {
                const int c = r / 10, j = r - c * 10;
                const int fc = (j < 5) ? c : c + 128;
                const int v  = (j < 5) ? j : j - 5;
                xs[gg][fc][v] = tmp[e];
                ++r;
            }
            (void)g;
        }
    }
    __syncthreads();

    // ---- matmul: fc = 0..255 sequential (acc half then gyr half), unfused
    float acc[4][NV];
    #pragma unroll
    for (int g = 0; g < 4; ++g)
        #pragma unroll
        for (int v = 0; v < NV; ++v) acc[g][v] = 0.f;

    #pragma unroll 4
    for (int fc = 0; fc < 256; ++fc) {
        const float A = Wt[fc * 128 + o];      // coalesced, L2-resident
        #pragma unroll
        for (int g = 0; g < 4; ++g) {
            const float4 xv = *(const float4*)&xs[g][fc][0];   // LDS broadcast
            const float  x4 = xs[g][fc][4];
            acc[g][0] = fa(acc[g][0], fm(A, xv.x));
            acc[g][1] = fa(acc[g][1], fm(A, xv.y));
            acc[g][2] = fa(acc[g][2], fm(A, xv.z));
            acc[g][3] = fa(acc[g][3], fm(A, xv.w));
            acc[g][4] = fa(acc[g][4], fm(A, x4));
        }
    }
    __syncthreads();   // xs dead; reuse region for stats buffers

    float* ys = xs_raw;          // [4][640]
    float* dsv = xs_raw + 2560;  // [4][640]

    #pragma unroll
    for (int g = 0; g < 4; ++g)
        #pragma unroll
        for (int v = 0; v < NV; ++v) ys[g * 640 + o * 5 + v] = acc[g][v];
    __syncthreads();

    // mean: numpy pairwise over 640 (o-major order)
    if (threadIdx.x < 16) {
        const int g = threadIdx.x >> 2, p = threadIdx.x & 3;
        const float b0 = base80(&ys[g * 640 + (2 * p) * 80]);
        const float b1 = base80(&ys[g * 640 + (2 * p + 1) * 80]);
        statA[g][p] = fa(b0, b1);
    }
    __syncthreads();
    if (threadIdx.x < 4) {
        const int g = threadIdx.x;
        const float tot = fa(fa(statA[g][0], statA[g][1]), fa(statA[g][2], statA[g][3]));
        muS[g] = __fdiv_rn(tot, 640.f);
    }
    __syncthreads();

    // var: (a - mu)^2 pairwise / 640
    #pragma unroll
    for (int g = 0; g < 4; ++g) {
        const float mu = muS[g];
        #pragma unroll
        for (int v = 0; v < NV; ++v) {
            const float d = fs(acc[g][v], mu);
            dsv[g * 640 + o * 5 + v] = fm(d, d);
        }
    }
    __syncthreads();
    if (threadIdx.x < 16) {
        const int g = threadIdx.x >> 2, p = threadIdx.x & 3;
        const float b0 = base80(&dsv[g * 640 + (2 * p) * 80]);
        const float b1 = base80(&dsv[g * 640 + (2 * p + 1) * 80]);
        statA[g][p] = fa(b0, b1);
    }
    __syncthreads();
    if (threadIdx.x < 4) {
        const int g = threadIdx.x;
        const float tot = fa(fa(statA[g][0], statA[g][1]), fa(statA[g][2], statA[g][3]));
        const float var = __fdiv_rn(tot, 640.f);
        rstdS[g] = __fdiv_rn(1.f, __fsqrt_rn(fa(var, 1e-5f)));
    }
    __syncthreads();

    const float wf = g1w[o], bf = g1b[o];
    #pragma unroll
    for (int g = 0; g < 4; ++g) {
        const float mu = muS[g], rstd = rstdS[g];
        const int n = n0 + g;
        #pragma unroll
        for (int v = 0; v < NV; ++v) {
            const float xn = fm(fs(acc[g][v], mu), rstd);
            y1[(size_t)n * 640 + o * 5 + v] = fa(fm(xn, wf), bf);
        }
    }
}

// =========================================================================
// Kernel B1: LIF1 (fp32, identical chain) -> ulonglong2 spike masks.
// =========================================================================
__global__ __launch_bounds__(320) void kB1(const float* __restrict__ y1,
                                           ulonglong2* __restrict__ masks)
{
    const int b   = blockIdx.x >> 1;
    const int c0  = (blockIdx.x & 1) * 64;
    const int tid = threadIdx.x;           // 0..319

    ull lo = 0ull, hi = 0ull;
    float vm = 0.f;
    const float* p = y1 + (size_t)b * 640 + (size_t)c0 * 5 + tid;
    for (int t0 = 0; t0 < NT; t0 += 16) {
        float xv[16];
        #pragma unroll
        for (int j = 0; j < 16; ++j)
            xv[j] = p[(size_t)(t0 + j) * (NB * 640)];
        #pragma unroll
        for (int j = 0; j < 16; ++j) {
            vm = fa(vm, fm(fs(xv[j], vm), 0.5f));
            if (vm >= 0.8f) {
                const int t = t0 + j;
                if (t < 64) lo |= 1ull << t; else hi |= 1ull << (t - 64);
                vm = 0.f;
            }
        }
    }
    masks[(size_t)b * 640 + (size_t)c0 * 5 + tid] = make_ulonglong2(lo, hi);
}

// =========================================================================
// Kernel B2: conv once (LDS) -> pairwise GN2 -> LIF2 -> coalesced stores.
// =========================================================================
__device__ __forceinline__ float bitf(ull lo, ull hi, int t)
{
    if (t < 0 || t > 127) return 0.f;
    return (float)(((t < 64) ? (lo >> t) : (hi >> (t - 64))) & 1ull);
}

__global__ __launch_bounds__(512) void kB2(const ulonglong2* __restrict__ masks,
                                           const float* __restrict__ Wm,
                                           const float* __restrict__ g2w,
                                           const float* __restrict__ g2b,
                                           const float* __restrict__ adj,
                                           float* __restrict__ out)
{
    const int blk = blockIdx.x;            // 0..4095
    const int b   = blk >> 5;              // 0..127
    const int c0  = (blk & 31) * 4;        // 0,4,..,124
    const int tid = threadIdx.x;           // 0..511
    const int p   = tid >> 7;              // pair 0..3
    const int lt  = tid & 127;             // t index / worker id

    __shared__ float mw_s[75];
    __shared__ ull   m_lo[4][5], m_hi[4][5];
    __shared__ float conv_s[4][5][128];
    __shared__ float spk_s[128][40];
    __shared__ float stat_s[4][8];
    __shared__ float mu_s[4], rstd_s[4];

    if (tid < 75) {
        const int oo = tid / 15, rem = tid % 15, ii = rem / 3;
        const float sym = fm(0.5f, fa(adj[oo * 5 + ii], adj[ii * 5 + oo]));
        const float e = (float)exp(-(double)sym);
        const float sig = __fdiv_rn(1.f, fa(1.f, e));
        mw_s[tid] = fm(Wm[tid], sig);
    }
    if (tid < 20) {
        const int pp = tid / 5, vv = tid % 5;
        const ulonglong2 m = masks[((size_t)b * 128 + c0 + pp) * 5 + vv];
        m_lo[pp][vv] = m.x; m_hi[pp][vv] = m.y;
    }
    __syncthreads();

    // ---- conv once: thread (p, t=lt); 15 shared bit extracts, 5 nodes
    {
        float bv[5][3];
        #pragma unroll
        for (int i = 0; i < 5; ++i) {
            const ull lo = m_lo[p][i], hi = m_hi[p][i];
            #pragma unroll
            for (int k = 0; k < 3; ++k)
                bv[i][k] = bitf(lo, hi, lt - 1 + k);
        }
        #pragma unroll
        for (int o = 0; o < 5; ++o) {
            float res = 0.f;
            #pragma unroll
            for (int i = 0; i < 5; ++i)
                #pragma unroll
                for (int k = 0; k < 3; ++k)
                    res = fa(res, fm(mw_s[(o * 5 + i) * 3 + k], bv[i][k]));
            conv_s[p][o][lt] = res;
        }
    }
    __syncthreads();

    // ---- GN2 mean
    if (lt < 8)
        stat_s[p][lt] = base80(&conv_s[p][0][0] + lt * 80);
    __syncthreads();
    if (lt == 0) {
        const float* s = stat_s[p];
        const float tot = fa(fa(fa(s[0],s[1]),fa(s[2],s[3])),
                             fa(fa(s[4],s[5]),fa(s[6],s[7])));
        mu_s[p] = __fdiv_rn(tot, 640.f);
    }
    __syncthreads();

    // ---- GN2 var
    if (lt < 8)
        stat_s[p][lt] = base80v(&conv_s[p][0][0] + lt * 80, mu_s[p]);
    __syncthreads();
    if (lt == 0) {
        const float* s = stat_s[p];
        const float tot = fa(fa(fa(s[0],s[1]),fa(s[2],s[3])),
                             fa(fa(s[4],s[5]),fa(s[6],s[7])));
        const float var = __fdiv_rn(tot, 640.f);
        rstd_s[p] = __fdiv_rn(1.f, __fsqrt_rn(fa(var, 1e-5f)));
    }
    __syncthreads();

    // ---- LIF2: 5 threads per pair (o = lt), spikes -> LDS
    if (lt < 5) {
        const int o = lt;
        const float mu = mu_s[p], rstd = rstd_s[p];
        const float gw = g2w[o], gb = g2b[o];
        float vm = 0.f;
        for (int t = 0; t < NT; ++t) {
            const float z  = conv_s[p][o][t];
            const float xn = fm(fs(z, mu), rstd);
            const float yn = fa(fm(xn, gw), gb);
            vm = fa(vm, fm(fs(yn, vm), 0.5f));
            const bool sp = (vm >= 0.8f);
            if (sp) vm = 0.f;
            const float so = sp ? 1.f : 0.f;
            spk_s[t][p * 10 + o]     = so;
            spk_s[t][p * 10 + 5 + o] = so;
        }
    }
    __syncthreads();

    // ---- coalesced store
    for (int q = tid; q < 1280; q += 512) {
        const int t = q / 10, s = q - t * 10;
        float4* dst = (float4*)(out + ((size_t)(t * NB + b) * 1280 + c0 * 10));
        dst[s] = reinterpret_cast<const float4*>(&spk_s[t][0])[s];
    }
}

// =========================================================================
extern "C" void kernel_launch(void* const* d_in, const int* in_sizes, int n_in,
                              void* d_out, int out_size, void* d_ws, size_t ws_size,
                              hipStream_t stream)
{
    const float* x   = (const float*)d_in[0];
    const float* W   = (const float*)d_in[1];
    const float* g1w = (const float*)d_in[2];
    const float* g1b = (const float*)d_in[3];
    const float* Wm  = (const float*)d_in[4];
    const float* g2w = (const float*)d_in[5];
    const float* g2b = (const float*)d_in[6];
    const float* adj = (const float*)d_in[7];
    float* out = (float*)d_out;

    float* y1 = (float*)d_ws;                                     // 41.9 MB
    ulonglong2* masks = (ulonglong2*)((char*)d_ws + (64u << 20)); // 1.3 MB
    float* Wt = (float*)((char*)d_ws + (80u << 20));              // 128 KB

    hipLaunchKernelGGL(kT, dim3(128), dim3(256), 0, stream, W, Wt);
    hipLaunchKernelGGL(kA, dim3(NT * NB / 4), dim3(128), 0, stream,
                       x, Wt, g1w, g1b, y1);
    hipLaunchKernelGGL(kB1, dim3(NB * 2), dim3(320), 0, stream,
                       y1, masks);
    hipLaunchKernelGGL(kB2, dim3(4096), dim3(512), 0, stream,
                       masks, Wm, g2w, g2b, adj, out);
}